// Round 1
// baseline (16609.204 us; speedup 1.0000x reference)
//
#include <hip/hip_runtime.h>
#include <cstdint>

typedef short short8 __attribute__((ext_vector_type(8)));
typedef float floatx4 __attribute__((ext_vector_type(4)));

#define TS 512
#define BB 64
#define HD 1024
#define MROWS (TS * BB) // 32768

__device__ __forceinline__ unsigned short f2bf(float f) {
    uint32_t u = __float_as_uint(f);
    u += 0x7fffu + ((u >> 16) & 1u); // RNE
    return (unsigned short)(u >> 16);
}

// ---------------- fp32 -> bf16 cast (vectorized) ----------------
__global__ __launch_bounds__(256) void cast_f32_bf16(const float* __restrict__ s,
                                                     unsigned short* __restrict__ d, int n4) {
    int i = blockIdx.x * 256 + threadIdx.x;
    if (i >= n4) return;
    float4 v = ((const float4*)s)[i];
    ushort4 o = make_ushort4(f2bf(v.x), f2bf(v.y), f2bf(v.z), f2bf(v.w));
    ((ushort4*)d)[i] = o;
}

// ---------------- input-projection GEMM ----------------
// C[M,2048] = A[M,K](bf16) * Bt[2048,K]^T + bias ; cols 0..1023 get biasF-1 (BETA), rest biasG
__global__ __launch_bounds__(256) void gemm_bt_bias(
    const unsigned short* __restrict__ A, const unsigned short* __restrict__ Bt,
    const float* __restrict__ biasF, const float* __restrict__ biasG,
    float* __restrict__ C, int M, int K)
{
    const int N = 2048;
    __shared__ unsigned short As[128 * 32];
    __shared__ unsigned short Bs[128 * 32];
    int bm = blockIdx.x * 128, bn = blockIdx.y * 128;
    int th = threadIdx.x;
    int wave = th >> 6, lane = th & 63;
    int lrow = lane & 15, quad = lane >> 4;
    int wm = (wave & 1) * 64, wn = (wave >> 1) * 64;
    const unsigned short* Ag = A + (size_t)bm * K;
    const unsigned short* Bg = Bt + (size_t)bn * K;

    floatx4 acc[4][4];
#pragma unroll
    for (int i = 0; i < 4; ++i)
#pragma unroll
        for (int j = 0; j < 4; ++j) acc[i][j] = (floatx4){0.f, 0.f, 0.f, 0.f};

    for (int k0 = 0; k0 < K; k0 += 32) {
        __syncthreads();
        // stage 128x32 A and B tiles, XOR-swizzled so frag reads are 2-way (free)
#pragma unroll
        for (int jj = 0; jj < 2; ++jj) {
            int c = jj * 256 + th;          // 512 16B chunks per tile
            int row = c >> 2, kk = c & 3;   // 4 chunks (32 elems) per row
            int ph = (row * 4 + (kk ^ ((row >> 1) & 3))) * 8;
            uint4 va = *(const uint4*)(Ag + (size_t)row * K + k0 + kk * 8);
            uint4 vb = *(const uint4*)(Bg + (size_t)row * K + k0 + kk * 8);
            *(uint4*)(As + ph) = va;
            *(uint4*)(Bs + ph) = vb;
        }
        __syncthreads();
        short8 af[4], bfv[4];
#pragma unroll
        for (int i = 0; i < 4; ++i) {
            int r = wm + i * 16 + lrow;
            af[i] = *(const short8*)(As + (r * 4 + (quad ^ ((r >> 1) & 3))) * 8);
        }
#pragma unroll
        for (int j = 0; j < 4; ++j) {
            int r = wn + j * 16 + lrow;
            bfv[j] = *(const short8*)(Bs + (r * 4 + (quad ^ ((r >> 1) & 3))) * 8);
        }
#pragma unroll
        for (int i = 0; i < 4; ++i)
#pragma unroll
            for (int j = 0; j < 4; ++j)
                acc[i][j] = __builtin_amdgcn_mfma_f32_16x16x32_bf16(af[i], bfv[j], acc[i][j], 0, 0, 0);
    }
    // epilogue: C/D layout col=lane&15, row=quad*4+reg (m89-verified)
#pragma unroll
    for (int j = 0; j < 4; ++j) {
        int col = bn + wn + j * 16 + lrow;
        float bias = (col < 1024) ? (biasF[col] - 1.0f) : biasG[col - 1024];
#pragma unroll
        for (int i = 0; i < 4; ++i) {
            int row0 = bm + wm + i * 16 + quad * 4;
#pragma unroll
            for (int r = 0; r < 4; ++r)
                C[(size_t)(row0 + r) * N + col] = acc[i][j][r] + bias;
        }
    }
}

// ---------------- persistent JANET recurrence ----------------
// 64 WGs x 256 threads. WG w owns hidden cols [16w,16w+16); wave v owns batch rows [16v,16v+16).
// Weights (both gates) LDS-resident for all T steps. One agent-scope flag barrier per step.
__global__ __launch_bounds__(256) void janet_scan(
    const float* __restrict__ P,        // [T*64, 2048]  (pf | pg), bias+(-BETA) already folded
    const unsigned short* __restrict__ Rf, // hfW bf16 [1024,1024]
    const unsigned short* __restrict__ Rg, // hgW bf16 [1024,1024]
    const float* __restrict__ hbf, const float* __restrict__ hbg,
    unsigned short* __restrict__ hbuf,  // [2][64][1024] bf16, buffer 0 zeroed
    int* flags,                         // [64], zeroed
    unsigned short* __restrict__ Ybf,   // layer0 output (bf16) or null
    float* __restrict__ Yf32)           // layer1 output (fp32) or null
{
    __shared__ unsigned short Wl[2][16 * 1024]; // 64 KiB, XOR-swizzled by (n&7)
    int w = blockIdx.x, th = threadIdx.x;
    int wave = th >> 6, lane = th & 63;
    int lrow = lane & 15, quad = lane >> 4;
    int c0 = w * 16;

    // load weight slices once: 4096 16B chunks (2 gates x 16 rows x 128 chunks)
    for (int c = th; c < 4096; c += 256) {
        int g = c >> 11, n = (c >> 7) & 15, k8 = c & 127;
        const unsigned short* src = (g ? Rg : Rf) + (size_t)(c0 + n) * 1024 + k8 * 8;
        *(uint4*)(&Wl[g][(n * 128 + (k8 ^ (n & 7))) * 8]) = *(const uint4*)src;
    }
    __syncthreads();

    int col = c0 + lrow;
    float bF = hbf[col], bG = hbg[col];
    float hr[4] = {0.f, 0.f, 0.f, 0.f};     // fp32 master h, C-layout (b=wave*16+quad*4+r)
    int myrow = wave * 16 + lrow;            // A-frag batch row
    int sw = lrow & 7;
    const unsigned short* w0 = &Wl[0][lrow << 10];
    const unsigned short* w1 = &Wl[1][lrow << 10];

    for (int t = 0; t < TS; ++t) {
        // prefetch P early (HBM latency hidden under the MFMA K-loop)
        float pf[4], pg[4];
        size_t pbase = ((size_t)t * 64 + wave * 16 + quad * 4) * 2048 + col;
#pragma unroll
        for (int r = 0; r < 4; ++r) {
            pf[r] = P[pbase + (size_t)r * 2048];
            pg[r] = P[pbase + (size_t)r * 2048 + 1024];
        }
        const unsigned short* hs = hbuf + ((size_t)(t & 1) << 16) + ((size_t)myrow << 10);
        floatx4 aF = {0.f, 0.f, 0.f, 0.f}, aG = {0.f, 0.f, 0.f, 0.f};
#pragma unroll 8
        for (int ks = 0; ks < 32; ++ks) {
            short8 a = *(const short8*)(hs + (ks << 5) + (quad << 3));
            int k8 = (ks << 2) + quad;
            short8 bf_ = *(const short8*)(w0 + ((k8 ^ sw) << 3));
            short8 bg_ = *(const short8*)(w1 + ((k8 ^ sw) << 3));
            aF = __builtin_amdgcn_mfma_f32_16x16x32_bf16(a, bf_, aF, 0, 0, 0);
            aG = __builtin_amdgcn_mfma_f32_16x16x32_bf16(a, bg_, aG, 0, 0, 0);
        }
        unsigned short* hd = hbuf + ((size_t)((t + 1) & 1) << 16);
#pragma unroll
        for (int r = 0; r < 4; ++r) {
            int b = wave * 16 + quad * 4 + r;
            float f = 1.f / (1.f + __expf(-(pf[r] + aF[r] + bF)));
            float xg = pg[r] + aG[r] + bG;
            xg = fminf(fmaxf(xg, -15.f), 15.f);
            float e2 = __expf(2.f * xg);
            float g = (e2 - 1.f) / (e2 + 1.f);
            float hn = f * hr[r] + (1.f - f) * g;
            hr[r] = hn;
            hd[(size_t)b * 1024 + col] = f2bf(hn);
            size_t yi = ((size_t)t * 64 + b) * 1024 + col;
            if (Ybf)  Ybf[yi] = f2bf(hn);
            if (Yf32) Yf32[yi] = hn;
        }
        // ---- grid barrier: release h writes, flag, poll all 64 WGs, acquire ----
        __builtin_amdgcn_fence(__ATOMIC_RELEASE, "agent");
        __syncthreads();
        if (th == 0)
            __hip_atomic_store(&flags[w], t + 1, __ATOMIC_RELAXED, __HIP_MEMORY_SCOPE_AGENT);
        int spins = 0;
        while (true) {
            int fv = __hip_atomic_load(&flags[lane], __ATOMIC_RELAXED, __HIP_MEMORY_SCOPE_AGENT);
            if (__all(fv >= t + 1)) break;
            if (++spins > 200000) break; // bail out loudly instead of hanging
        }
        __builtin_amdgcn_fence(__ATOMIC_ACQUIRE, "agent");
    }
}

extern "C" void kernel_launch(void* const* d_in, const int* in_sizes, int n_in,
                              void* d_out, int out_size, void* d_ws, size_t ws_size,
                              hipStream_t stream) {
    (void)in_sizes; (void)n_in; (void)out_size; (void)ws_size;
    const float* X    = (const float*)d_in[0];
    const float* ifW0 = (const float*)d_in[1];
    const float* ifB0 = (const float*)d_in[2];
    const float* hfW0 = (const float*)d_in[3];
    const float* hfB0 = (const float*)d_in[4];
    const float* igW0 = (const float*)d_in[5];
    const float* igB0 = (const float*)d_in[6];
    const float* hgW0 = (const float*)d_in[7];
    const float* hgB0 = (const float*)d_in[8];
    const float* ifW1 = (const float*)d_in[9];
    const float* ifB1 = (const float*)d_in[10];
    const float* hfW1 = (const float*)d_in[11];
    const float* hfB1 = (const float*)d_in[12];
    const float* igW1 = (const float*)d_in[13];
    const float* igB1 = (const float*)d_in[14];
    const float* hgW1 = (const float*)d_in[15];
    const float* hgB1 = (const float*)d_in[16];

    char* p = (char*)d_ws;
    auto alloc = [&](size_t bytes) {
        char* r = p; p += (bytes + 255) & ~(size_t)255; return r;
    };
    float* P            = (float*)alloc((size_t)MROWS * 2048 * 4);       // 256 MB
    unsigned short* Y0  = (unsigned short*)alloc((size_t)MROWS * 1024 * 2); // 64 MB
    unsigned short* Xb  = (unsigned short*)alloc((size_t)MROWS * 512 * 2);  // 32 MB
    unsigned short* W0c = (unsigned short*)alloc((size_t)2048 * 512 * 2);
    unsigned short* W1c = (unsigned short*)alloc((size_t)2048 * 1024 * 2);
    unsigned short* Rf0 = (unsigned short*)alloc((size_t)1024 * 1024 * 2);
    unsigned short* Rg0 = (unsigned short*)alloc((size_t)1024 * 1024 * 2);
    unsigned short* Rf1 = (unsigned short*)alloc((size_t)1024 * 1024 * 2);
    unsigned short* Rg1 = (unsigned short*)alloc((size_t)1024 * 1024 * 2);
    unsigned short* hbuf = (unsigned short*)alloc((size_t)2 * 64 * 1024 * 2);
    int* flags0 = (int*)alloc(256);
    int* flags1 = (int*)alloc(256);

    // ws is poisoned 0xAA every call: zero h state + barrier flags
    hipMemsetAsync(hbuf, 0, (size_t)2 * 64 * 1024 * 2, stream);
    hipMemsetAsync(flags0, 0, 512, stream); // flags0 + flags1 are contiguous

    auto cast = [&](const float* s, unsigned short* d, size_t n) {
        int n4 = (int)(n / 4);
        cast_f32_bf16<<<dim3((n4 + 255) / 256), dim3(256), 0, stream>>>(s, d, n4);
    };
    cast(X, Xb, (size_t)MROWS * 512);
    cast(ifW0, W0c, (size_t)1024 * 512);
    cast(igW0, W0c + (size_t)1024 * 512, (size_t)1024 * 512);
    cast(ifW1, W1c, (size_t)1024 * 1024);
    cast(igW1, W1c + (size_t)1024 * 1024, (size_t)1024 * 1024);
    cast(hfW0, Rf0, (size_t)1024 * 1024);
    cast(hgW0, Rg0, (size_t)1024 * 1024);
    cast(hfW1, Rf1, (size_t)1024 * 1024);
    cast(hgW1, Rg1, (size_t)1024 * 1024);

    // layer 0
    gemm_bt_bias<<<dim3(MROWS / 128, 16), dim3(256), 0, stream>>>(Xb, W0c, ifB0, igB0, P, MROWS, 512);
    janet_scan<<<dim3(64), dim3(256), 0, stream>>>(P, Rf0, Rg0, hfB0, hgB0, hbuf, flags0, Y0, nullptr);

    // layer 1
    hipMemsetAsync(hbuf, 0, (size_t)2 * 64 * 1024 * 2, stream);
    gemm_bt_bias<<<dim3(MROWS / 128, 16), dim3(256), 0, stream>>>(Y0, W1c, ifB1, igB1, P, MROWS, 1024);
    janet_scan<<<dim3(64), dim3(256), 0, stream>>>(P, Rf1, Rg1, hfB1, hgB1, hbuf, flags1, nullptr, (float*)d_out);
}